// Round 5
// baseline (68886.743 us; speedup 1.0000x reference)
//
#include <hip/hip_runtime.h>

// ---------------- problem constants ----------------
#define Tn   512
#define Bn   64
#define NWG  256
#define NTH  256

// ---------------- ws layout (float words) ----------------
#define OFF_WCOMB 0               // [2048][256]
#define OFF_BC0   524288          // [2048]
#define OFF_EMBG  526336          // [11][2048]
#define OFF_H0T   548864          // [2][512*64]  (zero region starts here)
#define OFF_H1T   (OFF_H0T + 65536)
#define OFF_C0T   (OFF_H1T + 65536)
#define OFF_C1T   (OFF_C0T + 32768)
#define OFF_BAR   (OFF_C1T + 32768)     // done-flag line (32 words)
#define OFF_ARR   (OFF_BAR + 32)        // 256 arrival slots * 32 words
#define OFF_TAG   (OFF_ARR + NWG * 32)  // 128 head tags * 32 words
#define ZERO_END  (OFF_TAG + 128 * 32)
#define ZERO_WORDS (ZERO_END - OFF_H0T)
#define OFF_PBUF  ZERO_END              // [704][128] floats (not zeroed)
#define WS_WORDS  (OFF_PBUF + 704 * 128)

// out layout: logits [64][512][11] = 360448, zeros 360448, attn 32768
#define OUT_LOGITS_WORDS 360448
#define OUT_TAIL_WORDS   393216

// ---------------- setup kernels ----------------
__global__ void k_wcomb(const float* __restrict__ Wih0, const float* __restrict__ Wp,
                        const float* __restrict__ bp, const float* __restrict__ bih0,
                        const float* __restrict__ bhh0, float* __restrict__ ws) {
    int j = blockIdx.x;            // 0..2047
    int k = threadIdx.x;           // 0..255
    const float* row = Wih0 + (long)j * 1024;
    float acc = 0.f;
    for (int h = 0; h < 512; ++h) acc = fmaf(row[h], Wp[h * 256 + k], acc);
    ws[OFF_WCOMB + j * 256 + k] = acc;
    // bc0[j] = bih0 + bhh0 + dot(Wih0[j,:512], bp)
    __shared__ float s[256];
    s[k] = row[k] * bp[k] + row[256 + k] * bp[256 + k];
    __syncthreads();
    for (int st = 128; st > 0; st >>= 1) { if (k < st) s[k] += s[k + st]; __syncthreads(); }
    if (k == 0) ws[OFF_BC0 + j] = bih0[j] + bhh0[j] + s[0];
}

__global__ void k_embg(const float* __restrict__ emb, const float* __restrict__ Wih0,
                       float* __restrict__ ws) {
    int cls = blockIdx.x >> 3;                       // 0..10
    int j = ((blockIdx.x & 7) << 8) + threadIdx.x;   // 0..2047
    const float* er = emb + cls * 512;
    const float* wr = Wih0 + (long)j * 1024 + 512;
    float acc = 0.f;
    for (int h = 0; h < 512; ++h) acc = fmaf(er[h], wr[h], acc);
    ws[OFF_EMBG + cls * 2048 + j] = acc;
}

// zero state + barrier/tag slots (MUST run every launch: graph replays reuse ws)
__global__ void k_zero(float* __restrict__ ws) {
    long i = (long)blockIdx.x * blockDim.x + threadIdx.x;
    if (i < ZERO_WORDS) ws[OFF_H0T + i] = 0.f;
}

// ---------------- main persistent kernel ----------------
struct MP {
    const float *mainf, *phys, *Whh0, *Wih1, *Whh1, *bih1, *bhh1, *W1, *b1, *W2, *b2;
    float* ws;
    float* out;
};

struct Seg {
    const float* act;   // base
    long rs;            // row stride (b-major); unused for kmaj
    int kmaj;           // 1: act[k*64+b]   0: act[b*rs+k]
    int klen;
    const float* wgt;   // weight base, row-major
    int wld;
    int wcol0;
};

__device__ __forceinline__ float sigm(float x) { return 1.f / (1.f + expf(-x)); }

__device__ __forceinline__ void resolve(int ch, int nch0, const Seg* sg, int& s, int& k0, int& kc) {
    if (ch < nch0) { s = 0; k0 = ch << 6; }
    else           { s = 1; k0 = (ch - nch0) << 6; }
    kc = sg[s].klen - k0; if (kc > 64) kc = 64;
}

// LDS act tile is TRANSPOSED: actT[k_within_chunk][batch], row stride 72.
template <int NI>
__device__ __forceinline__ void stage_chunk(int ch, int nch0, const Seg* sg, int j0, int jstride,
                                            int tid, float (*act)[72], float (*wt)[68]) {
    int s, k0, kc; resolve(ch, nch0, sg, s, k0, kc);
    const Seg g = sg[s];
    if (g.kmaj) {
        #pragma unroll
        for (int ii = 0; ii < 4; ++ii) {
            int e = tid + (ii << 8);          // 0..1023
            int b4 = e & 15, kk = e >> 4;     // b4: float4-of-batch, kk: 0..63
            if (kk < kc) {
                float4 v = *(const float4*)(g.act + ((long)(k0 + kk) << 6) + (b4 << 2));
                *(float4*)&act[kk][b4 << 2] = v;
            }
        }
    } else {
        #pragma unroll
        for (int ii = 0; ii < 4; ++ii) {
            int e = tid + (ii << 8);
            int k4 = e >> 6, bb = e & 63;     // k4 0..15, bb 0..63
            if ((k4 << 2) < kc) {
                float4 v = *(const float4*)(g.act + (long)bb * g.rs + k0 + (k4 << 2));
                act[(k4 << 2) + 0][bb] = v.x;
                act[(k4 << 2) + 1][bb] = v.y;
                act[(k4 << 2) + 2][bb] = v.z;
                act[(k4 << 2) + 3][bb] = v.w;
            }
        }
    }
    // weights: NI*2 rows of 64 (row-major, broadcast-read in compute)
    for (int e = tid; e < ((NI * 2) << 6); e += 256) {
        int rw = e >> 6, kk = e & 63;
        if (kk < kc) {
            int j = (rw >> 1) * jstride + j0 + (rw & 1);
            wt[rw][kk] = g.wgt[(long)j * g.wld + g.wcol0 + k0 + kk];
        }
    }
}

// acc[i] = sum_k act[k] * W[j(i)][k],  j(i) = i*jstride + j0 + c.
// q in {0,1} splits K; owner threads (q==0, tid<128) hold the full sum on return.
template <int NI>
__device__ void mm_quads(const Seg* sg, int nseg, int j0, int jstride, float* acc,
                         int tid, int b, int c, int q,
                         float (*actA)[72], float (*actB)[72],
                         float (*wAr)[68], float (*wBr)[68],
                         float (*red)[64][4]) {
    #pragma unroll
    for (int i = 0; i < NI; ++i) acc[i] = 0.f;
    int nch0 = (sg[0].klen + 63) >> 6;
    int nch  = nch0 + ((nseg > 1) ? ((sg[1].klen + 63) >> 6) : 0);
    int nq0  = (nch + 1) >> 1;
    for (int it = 0; it < nq0; ++it) {
        int chA = it, chB = nq0 + it;
        stage_chunk<NI>(chA, nch0, sg, j0, jstride, tid, actA, wAr);
        if (chB < nch) stage_chunk<NI>(chB, nch0, sg, j0, jstride, tid, actB, wBr);
        __syncthreads();
        int myc = q ? chB : chA;
        if (myc < nch) {
            int s, k0, kc; resolve(myc, nch0, sg, s, k0, kc);
            float (*at)[72] = q ? actB : actA;
            float (*wv)[68] = q ? wBr : wAr;
            int n4 = kc >> 2;
            for (int k4 = 0; k4 < n4; ++k4) {
                float a0 = at[(k4 << 2) + 0][b];
                float a1 = at[(k4 << 2) + 1][b];
                float a2 = at[(k4 << 2) + 2][b];
                float a3 = at[(k4 << 2) + 3][b];
                #pragma unroll
                for (int i = 0; i < NI; ++i) {
                    float4 w4 = *(const float4*)&wv[i * 2 + c][k4 << 2];
                    acc[i] = fmaf(a0, w4.x, acc[i]);
                    acc[i] = fmaf(a1, w4.y, acc[i]);
                    acc[i] = fmaf(a2, w4.z, acc[i]);
                    acc[i] = fmaf(a3, w4.w, acc[i]);
                }
            }
        }
        __syncthreads();
    }
    if (q == 1) {
        #pragma unroll
        for (int i = 0; i < NI; ++i) red[c][b][i] = acc[i];
    }
    __syncthreads();
    if (q == 0) {
        #pragma unroll
        for (int i = 0; i < NI; ++i) acc[i] += red[c][b][i];
    }
    __syncthreads();
}

// Contention-free broadcast barrier: per-WG arrival slot (release store),
// WG0 aggregates (256 threads poll 1 slot each), publishes done=gen. No RMW.
__device__ __forceinline__ void gsync(int* done, int* arr, int w, int gen) {
    __syncthreads();
    const int tid = threadIdx.x;
    if (tid == 0) {
        __threadfence();
        __hip_atomic_store(&arr[w * 32], gen, __ATOMIC_RELEASE, __HIP_MEMORY_SCOPE_AGENT);
    }
    if (w == 0) {
        int v;
        do {
            __builtin_amdgcn_s_sleep(1);
            v = __hip_atomic_load(&arr[tid * 32], __ATOMIC_RELAXED, __HIP_MEMORY_SCOPE_AGENT);
        } while (v < gen);
        __syncthreads();
        if (tid == 0) {
            __threadfence();
            __hip_atomic_store(done, gen, __ATOMIC_RELEASE, __HIP_MEMORY_SCOPE_AGENT);
        }
    } else {
        if (tid == 0) {
            int v;
            do {
                __builtin_amdgcn_s_sleep(2);
                v = __hip_atomic_load(done, __ATOMIC_RELAXED, __HIP_MEMORY_SCOPE_AGENT);
            } while (v < gen);
            __threadfence();
        }
    }
    __syncthreads();
}

__global__ void __launch_bounds__(NTH, 1) k_main(MP p) {
    float* ws = p.ws;
    const float* Wcomb = ws + OFF_WCOMB;
    const float* bc0v  = ws + OFF_BC0;
    const float* embg  = ws + OFF_EMBG;
    float* h0T = ws + OFF_H0T;   // [2][512*64] k-major
    float* h1T = ws + OFF_H1T;
    float* c0T = ws + OFF_C0T;   // [512*64]
    float* c1T = ws + OFF_C1T;
    float* pbuf = ws + OFF_PBUF; // [704][128]  (b*11+cc major, w minor)
    int* done = (int*)(ws + OFF_BAR);
    int* arr  = (int*)(ws + OFF_ARR);
    int* tag  = (int*)(ws + OFF_TAG);

    __shared__ float actA[64][72], actB[64][72];
    __shared__ float wAr[8][68], wBr[8][68];
    __shared__ float red[2][64][4];
    __shared__ float plog[2][64][11];
    __shared__ float slog[704];
    __shared__ int prevl[64];

    const int w = blockIdx.x, tid = threadIdx.x;
    const int b = tid & 63, qc = tid >> 6, c = qc & 1, q = qc >> 1;
    int gen = 0;

    for (int t = 0; t <= Tn; ++t) {
        const int cur = t & 1, prv = cur ^ 1;

        // ---------- head partials for step t-1 (128 WGs), publish via tag ----------
        if (t >= 1 && w < 128) {
            Seg sg[2];
            sg[0] = { h1T + prv * 32768, 0, 1, 512, p.W1, 544, 0 };
            sg[1] = { p.phys + (long)(t - 1) * 32, (long)Tn * 32, 0, 32, p.W1, 544, 512 };
            float acc[2];
            mm_quads<2>(sg, 2, 4 * w, 2, acc, tid, b, c, q, actA, actB, wAr, wBr, red);
            if (q == 0) {
                int jh0 = 4 * w + c, jh1 = 2 + 4 * w + c;
                float r0 = acc[0] + p.b1[jh0]; r0 = r0 > 0.f ? r0 : 0.f;
                float r1 = acc[1] + p.b1[jh1]; r1 = r1 > 0.f ? r1 : 0.f;
                #pragma unroll
                for (int cc = 0; cc < 11; ++cc)
                    plog[c][b][cc] = fmaf(r0, p.W2[cc * 512 + jh0], r1 * p.W2[cc * 512 + jh1]);
            }
            __syncthreads();
            if (tid < 64) {
                #pragma unroll
                for (int cc = 0; cc < 11; ++cc)
                    pbuf[(long)(b * 11 + cc) * 128 + w] = plog[0][b][cc] + plog[1][b][cc];
            }
            __syncthreads();
            if (tid == 0) {
                __threadfence();
                __hip_atomic_store(&tag[w * 32], t, __ATOMIC_RELEASE, __HIP_MEMORY_SCOPE_AGENT);
            }
        }

        // ---------- every WG: reduce partials in fixed order, argmax ----------
        if (t >= 1) {
            if (tid < 128) {
                int v;
                do {
                    __builtin_amdgcn_s_sleep(1);
                    v = __hip_atomic_load(&tag[tid * 32], __ATOMIC_RELAXED, __HIP_MEMORY_SCOPE_AGENT);
                } while (v < t);
            }
            __syncthreads();
            __threadfence();   // acquire side: drop stale L1/L2 lines before pbuf reads
            #pragma unroll
            for (int r = 0; r < 3; ++r) {
                int pi = tid + (r << 8);
                if (pi < 704) {
                    const float* pb = pbuf + (long)pi * 128;
                    float s = 0.f;
                    for (int i = 0; i < 32; ++i) {
                        float4 v = *(const float4*)(pb + (i << 2));
                        s += v.x; s += v.y; s += v.z; s += v.w;
                    }
                    slog[pi] = s;
                }
            }
            __syncthreads();
            if (tid < 64) {
                float best = -3.4e38f; int am = 0;
                for (int cc = 0; cc < 11; ++cc) {
                    float v = slog[b * 11 + cc] + p.b2[cc];
                    if (w == 0) p.out[(long)b * (Tn * 11) + (long)(t - 1) * 11 + cc] = v;
                    if (v > best) { best = v; am = cc; }
                }
                prevl[b] = am;
            }
        } else {
            if (tid < 64) prevl[b] = 0;
        }
        __syncthreads();
        if (t == Tn) break;

        // ---------- gates0 GEMM + LSTM0 elementwise ----------
        {
            Seg sg[2];
            sg[0] = { p.mainf + (long)t * 256, (long)Tn * 256, 0, 256, Wcomb, 256, 0 };
            sg[1] = { h0T + prv * 32768, 0, 1, 512, p.Whh0, 512, 0 };
            float acc[4];
            mm_quads<4>(sg, 2, 2 * w, 512, acc, tid, b, c, q, actA, actB, wAr, wBr, red);
            if (q == 0) {
                int k = 2 * w + c;
                int pv = prevl[b];
                const float* eg = embg + pv * 2048;
                float g0 = acc[0] + bc0v[k]        + eg[k];
                float g1 = acc[1] + bc0v[k + 512]  + eg[k + 512];
                float g2 = acc[2] + bc0v[k + 1024] + eg[k + 1024];
                float g3 = acc[3] + bc0v[k + 1536] + eg[k + 1536];
                float ci = c0T[k * 64 + b];
                float cn = sigm(g1) * ci + sigm(g0) * tanhf(g2);
                c0T[k * 64 + b] = cn;
                h0T[cur * 32768 + k * 64 + b] = sigm(g3) * tanhf(cn);
            }
        }
        gsync(done, arr, w, ++gen);

        // ---------- gates1 GEMM + LSTM1 elementwise ----------
        {
            Seg sg[2];
            sg[0] = { h0T + cur * 32768, 0, 1, 512, p.Wih1, 512, 0 };
            sg[1] = { h1T + prv * 32768, 0, 1, 512, p.Whh1, 512, 0 };
            float acc[4];
            mm_quads<4>(sg, 2, 2 * w, 512, acc, tid, b, c, q, actA, actB, wAr, wBr, red);
            if (q == 0) {
                int k = 2 * w + c;
                float g0 = acc[0] + p.bih1[k]        + p.bhh1[k];
                float g1 = acc[1] + p.bih1[k + 512]  + p.bhh1[k + 512];
                float g2 = acc[2] + p.bih1[k + 1024] + p.bhh1[k + 1024];
                float g3 = acc[3] + p.bih1[k + 1536] + p.bhh1[k + 1536];
                float ci = c1T[k * 64 + b];
                float cn = sigm(g1) * ci + sigm(g0) * tanhf(g2);
                c1T[k * 64 + b] = cn;
                h1T[cur * 32768 + k * 64 + b] = sigm(g3) * tanhf(cn);
            }
        }
        gsync(done, arr, w, ++gen);
    }
}

// ---------------- launch ----------------
extern "C" void kernel_launch(void* const* d_in, const int* in_sizes, int n_in,
                              void* d_out, int out_size, void* d_ws, size_t ws_size,
                              hipStream_t stream) {
    const float* mainf = (const float*)d_in[0];
    const float* phys  = (const float*)d_in[1];
    // d_in[2] = mask (unused)
    const float* Wp   = (const float*)d_in[3];
    const float* bp   = (const float*)d_in[4];
    const float* emb  = (const float*)d_in[5];
    const float* Wih0 = (const float*)d_in[6];
    const float* Whh0 = (const float*)d_in[7];
    const float* bih0 = (const float*)d_in[8];
    const float* bhh0 = (const float*)d_in[9];
    const float* Wih1 = (const float*)d_in[10];
    const float* Whh1 = (const float*)d_in[11];
    const float* bih1 = (const float*)d_in[12];
    const float* bhh1 = (const float*)d_in[13];
    const float* W1   = (const float*)d_in[14];
    const float* b1   = (const float*)d_in[15];
    const float* W2   = (const float*)d_in[16];
    const float* b2   = (const float*)d_in[17];
    float* out = (float*)d_out;
    float* ws  = (float*)d_ws;

    // zeros for output 2 (zeros_like) and output 3 (attn)
    (void)hipMemsetAsync(out + OUT_LOGITS_WORDS, 0, (size_t)OUT_TAIL_WORDS * 4, stream);

    k_wcomb<<<2048, 256, 0, stream>>>(Wih0, Wp, bp, bih0, bhh0, ws);
    k_embg<<<88, 256, 0, stream>>>(emb, Wih0, ws);
    k_zero<<<(ZERO_WORDS + 255) / 256, 256, 0, stream>>>(ws);

    MP p{ mainf, phys, Whh0, Wih1, Whh1, bih1, bhh1, W1, b1, W2, b2, ws, out };
    k_main<<<NWG, NTH, 0, stream>>>(p);
}

// Round 6
// 26069.641 us; speedup vs baseline: 2.6424x; 2.6424x over previous
//
#include <hip/hip_runtime.h>

// ---------------- problem constants ----------------
#define Tn   512
#define NWG  256
#define NTH  1024

// ---------------- ws layout (float words) ----------------
#define OFF_WCOMB 0                      // [2048][256]
#define OFF_BC0   524288                 // [2048]
#define OFF_EMBG  526336                 // [11][2048]
#define OFF_H0T   548864                 // [2][512*64] k-major (zero region start)
#define OFF_H1T   (OFF_H0T + 65536)      // [2][512*64]
#define OFF_C0T   (OFF_H1T + 65536)      // [512*64]
#define OFF_C1T   (OFF_C0T + 32768)
#define OFF_BAR   (OFF_C1T + 32768)      // done flag (32 words)
#define OFF_ARR   (OFF_BAR + 32)         // 256 arrival slots * 32
#define OFF_TAG1  (OFF_ARR + 8192)       // 256 head tags * 32
#define OFF_PTAG  (OFF_TAG1 + 8192)      // 64 prev tags * 32
#define ZERO_END  (OFF_PTAG + 2048)
#define ZERO_WORDS (ZERO_END - OFF_H0T)
#define OFF_PBUF  ZERO_END               // [704][256] floats (overwritten each step)
#define WS_WORDS  (OFF_PBUF + 704 * 256)

// out layout: logits [64][512][11] = 360448, zeros 360448, attn 32768
#define OUT_LOGITS_WORDS 360448
#define OUT_TAIL_WORDS   393216

// ---------------- setup kernels ----------------
__global__ void k_wcomb(const float* __restrict__ Wih0, const float* __restrict__ Wp,
                        const float* __restrict__ bp, const float* __restrict__ bih0,
                        const float* __restrict__ bhh0, float* __restrict__ ws) {
    int j = blockIdx.x;            // 0..2047
    int k = threadIdx.x;           // 0..255
    const float* row = Wih0 + (long)j * 1024;
    float acc = 0.f;
    for (int h = 0; h < 512; ++h) acc = fmaf(row[h], Wp[h * 256 + k], acc);
    ws[OFF_WCOMB + j * 256 + k] = acc;
    __shared__ float s[256];
    s[k] = row[k] * bp[k] + row[256 + k] * bp[256 + k];
    __syncthreads();
    for (int st = 128; st > 0; st >>= 1) { if (k < st) s[k] += s[k + st]; __syncthreads(); }
    if (k == 0) ws[OFF_BC0 + j] = bih0[j] + bhh0[j] + s[0];
}

__global__ void k_embg(const float* __restrict__ emb, const float* __restrict__ Wih0,
                       float* __restrict__ ws) {
    int cls = blockIdx.x >> 3;
    int j = ((blockIdx.x & 7) << 8) + threadIdx.x;
    const float* er = emb + cls * 512;
    const float* wr = Wih0 + (long)j * 1024 + 512;
    float acc = 0.f;
    for (int h = 0; h < 512; ++h) acc = fmaf(er[h], wr[h], acc);
    ws[OFF_EMBG + cls * 2048 + j] = acc;
}

// zero state + tags/barrier (MUST run every launch: graph replays reuse ws)
__global__ void k_zero(float* __restrict__ ws) {
    long i = (long)blockIdx.x * blockDim.x + threadIdx.x;
    if (i < ZERO_WORDS) ws[OFF_H0T + i] = 0.f;
}

// ---------------- main persistent kernel ----------------
struct MP {
    const float *mainf, *phys, *Whh0, *Wih1, *Whh1, *bih1, *bhh1, *W1, *b1, *W2, *b2;
    float* ws;
    float* out;
};

struct Seg {
    const float* act;   // base
    long rs;            // row stride (b-major)
    int kmaj;           // 1: act[k*64+b]  0: act[b*rs+k]
    int klen;
    const float* wgt;   // weight base, row-major
    int wld;
    int wcol0;
    int coh;            // 1: stage act via sc0/sc1 bypass loads (cross-XCD data)
};

__device__ __forceinline__ float sigm(float x) { return 1.f / (1.f + expf(-x)); }

// coherent 16B load: bypass L1+L2, read from IC (cross-XCD-safe)
__device__ __forceinline__ void coh_issue16(const float* p, float4& v) {
    asm volatile("global_load_dwordx4 %0, %1, off sc0 sc1" : "=&v"(v) : "v"(p));
}
__device__ __forceinline__ void vm_wait0() {
    asm volatile("s_waitcnt vmcnt(0)" ::: "memory");
}
// coherent 4B store: write-through to IC (no fence needed for visibility)
__device__ __forceinline__ void coh_store(float* p, float v) {
    __hip_atomic_store(p, v, __ATOMIC_RELAXED, __HIP_MEMORY_SCOPE_AGENT);
}

__device__ __forceinline__ void resolve(int ch, int nch0, const Seg* sg, int& s, int& k0, int& kc) {
    if (ch < nch0) { s = 0; k0 = ch << 6; }
    else           { s = 1; k0 = (ch - nch0) << 6; }
    kc = sg[s].klen - k0; if (kc > 64) kc = 64;
}

// acc = sum_k act[b][k] * W[jrow(r)][k];  jrow(r) = (r>>1)*jstride + j0 + (r&1).
// Threads: b = tid&63, rq = tid>>6; r = rq & (NR-1), q = rq / NR; NQ=2 K-split.
// On return threads with rq < NR (q==0) hold the full sum.
template <int NR>
__device__ float mm_run(const Seg* sg, int j0, int jstride, int tid, int b,
                        float (*actA)[72], float (*actB)[72],
                        float (*wA)[68], float (*wB)[68], float (*red)[64]) {
    const int rq = tid >> 6;
    const int r = rq & (NR - 1);
    const int q = rq / NR;
    const int nch0 = (sg[0].klen + 63) >> 6;
    const int nch = nch0 + ((sg[1].klen + 63) >> 6);
    const int nq0 = (nch + 1) >> 1;
    float acc = 0.f;
    for (int it = 0; it < nq0; ++it) {
        const int chA = it, chB = nq0 + it;
        const bool hasB = chB < nch;
        int sA, kA, kcA; resolve(chA, nch0, sg, sA, kA, kcA);
        int sB = 0, kB = 0, kcB = 0;
        if (hasB) resolve(chB, nch0, sg, sB, kB, kcB);
        const Seg gA = sg[sA];
        const Seg gB = sg[sB];
        // ---- issue act loads (keep multiple in flight before the wait) ----
        float4 va, vb;
        bool stA = false, stB = false, coh = false;
        if (gA.kmaj) {
            const float* pa = gA.act + ((long)(kA + (tid >> 4)) << 6) + ((tid & 15) << 2);
            stA = true;
            if (gA.coh) { coh_issue16(pa, va); coh = true; } else va = *(const float4*)pa;
        } else {
            int k4 = tid >> 6, bb = tid & 63;
            if ((k4 << 2) < kcA) {
                const float* pa = gA.act + (long)bb * gA.rs + kA + (k4 << 2);
                stA = true;
                if (gA.coh) { coh_issue16(pa, va); coh = true; } else va = *(const float4*)pa;
            }
        }
        if (hasB) {
            if (gB.kmaj) {
                const float* pb = gB.act + ((long)(kB + (tid >> 4)) << 6) + ((tid & 15) << 2);
                stB = true;
                if (gB.coh) { coh_issue16(pb, vb); coh = true; } else vb = *(const float4*)pb;
            } else {
                int k4 = tid >> 6, bb = tid & 63;
                if ((k4 << 2) < kcB) {
                    const float* pb = gB.act + (long)bb * gB.rs + kB + (k4 << 2);
                    stB = true;
                    if (gB.coh) { coh_issue16(pb, vb); coh = true; } else vb = *(const float4*)pb;
                }
            }
        }
        // ---- weights (plain, read-only, L2-warm) ----
        float wva = 0.f, wvb = 0.f;
        const int rw = tid >> 6, kk = tid & 63;
        const bool wact = rw < NR;
        if (wact) {
            int j = (rw >> 1) * jstride + j0 + (rw & 1);
            if (kk < kcA) wva = gA.wgt[(long)j * gA.wld + gA.wcol0 + kA + kk];
            if (hasB && kk < kcB) wvb = gB.wgt[(long)j * gB.wld + gB.wcol0 + kB + kk];
        }
        if (coh) vm_wait0();
        // ---- LDS writes ----
        if (stA) {
            if (gA.kmaj) *(float4*)&actA[tid >> 4][(tid & 15) << 2] = va;
            else {
                int k4 = tid >> 6, bb = tid & 63;
                actA[(k4 << 2) + 0][bb] = va.x; actA[(k4 << 2) + 1][bb] = va.y;
                actA[(k4 << 2) + 2][bb] = va.z; actA[(k4 << 2) + 3][bb] = va.w;
            }
        }
        if (stB) {
            if (gB.kmaj) *(float4*)&actB[tid >> 4][(tid & 15) << 2] = vb;
            else {
                int k4 = tid >> 6, bb = tid & 63;
                actB[(k4 << 2) + 0][bb] = vb.x; actB[(k4 << 2) + 1][bb] = vb.y;
                actB[(k4 << 2) + 2][bb] = vb.z; actB[(k4 << 2) + 3][bb] = vb.w;
            }
        }
        if (wact) { wA[rw][kk] = wva; if (hasB) wB[rw][kk] = wvb; }
        __syncthreads();
        // ---- compute ----
        if (rq < NR * 2) {
            const int myc = q ? chB : chA;
            if (myc < nch) {
                int s, k0c, kc; resolve(myc, nch0, sg, s, k0c, kc);
                float (*at)[72] = q ? actB : actA;
                float (*wv)[68] = q ? wB : wA;
                const int n4 = kc >> 2;
                #pragma unroll 8
                for (int k4 = 0; k4 < n4; ++k4) {
                    float a0 = at[(k4 << 2) + 0][b];
                    float a1 = at[(k4 << 2) + 1][b];
                    float a2 = at[(k4 << 2) + 2][b];
                    float a3 = at[(k4 << 2) + 3][b];
                    float4 w4 = *(const float4*)&wv[r][k4 << 2];
                    acc = fmaf(a0, w4.x, acc);
                    acc = fmaf(a1, w4.y, acc);
                    acc = fmaf(a2, w4.z, acc);
                    acc = fmaf(a3, w4.w, acc);
                }
            }
        }
        __syncthreads();
    }
    if (rq >= NR && rq < NR * 2) red[r][b] = acc;   // q==1 partial
    __syncthreads();
    if (rq < NR) acc += red[r][b];                  // q==0 owner
    return acc;
}

// Fence-free barrier: vmcnt-drain per wave (all cross-WG data was written via
// coh_store -> already at IC), relaxed arrival tags, WG0 aggregates, relaxed done.
__device__ __forceinline__ void gsync(int* done, int* arr, int w, int gen) {
    vm_wait0();
    __syncthreads();
    const int tid = threadIdx.x;
    if (tid == 0)
        __hip_atomic_store(&arr[w * 32], gen, __ATOMIC_RELAXED, __HIP_MEMORY_SCOPE_AGENT);
    if (w == 0) {
        if (tid < NWG) {
            int v;
            do {
                __builtin_amdgcn_s_sleep(1);
                v = __hip_atomic_load(&arr[tid * 32], __ATOMIC_RELAXED, __HIP_MEMORY_SCOPE_AGENT);
            } while (v < gen);
        }
        __syncthreads();
        if (tid == 0)
            __hip_atomic_store(done, gen, __ATOMIC_RELAXED, __HIP_MEMORY_SCOPE_AGENT);
    } else {
        if (tid == 0) {
            int v;
            do {
                __builtin_amdgcn_s_sleep(2);
                v = __hip_atomic_load(done, __ATOMIC_RELAXED, __HIP_MEMORY_SCOPE_AGENT);
            } while (v < gen);
        }
    }
    __syncthreads();
}

__global__ void __launch_bounds__(NTH, 4) k_main(MP p) {
    float* ws = p.ws;
    const float* Wcomb = ws + OFF_WCOMB;
    const float* bc0v  = ws + OFF_BC0;
    const float* embg  = ws + OFF_EMBG;
    float* h0T = ws + OFF_H0T;
    float* h1T = ws + OFF_H1T;
    float* c0T = ws + OFF_C0T;
    float* c1T = ws + OFF_C1T;
    float* pbuf = ws + OFF_PBUF;            // [704][256]
    int* done = (int*)(ws + OFF_BAR);
    int* arr  = (int*)(ws + OFF_ARR);
    int* tag1 = (int*)(ws + OFF_TAG1);
    int* ptag = (int*)(ws + OFF_PTAG);

    __shared__ float actA[64][72], actB[64][72];
    __shared__ float wA[8][68], wB[8][68];
    __shared__ float red[8][64];
    __shared__ float rrow[2][64];
    __shared__ float slog[11];
    __shared__ int prevlS[64];

    const int w = blockIdx.x, tid = threadIdx.x, b = tid & 63;
    int gen = 0;

    for (int t = 0; t <= Tn; ++t) {
        const int cur = t & 1, prv = cur ^ 1;

        // ---------- head partials for step t-1 (all 256 WGs, 2 W1-rows each) ----------
        if (t >= 1) {
            Seg sg[2];
            sg[0] = { h1T + prv * 32768, 0, 1, 512, p.W1, 544, 0, 1 };
            sg[1] = { p.phys + (long)(t - 1) * 32, (long)Tn * 32, 0, 32, p.W1, 544, 512, 0 };
            float ha = mm_run<2>(sg, 2 * w, 512, tid, b, actA, actB, wA, wB, red);
            if (tid < 128) {
                float rr = ha + p.b1[2 * w + (tid >> 6)];
                rrow[tid >> 6][b] = rr > 0.f ? rr : 0.f;
            }
            __syncthreads();
            if (tid < 64) {
                float r0 = rrow[0][b], r1 = rrow[1][b];
                #pragma unroll
                for (int cc = 0; cc < 11; ++cc)
                    coh_store(&pbuf[((long)(b * 11 + cc) << 8) + w],
                              fmaf(r0, p.W2[cc * 512 + 2 * w], r1 * p.W2[cc * 512 + 2 * w + 1]));
            }
            if (tid == 0) {
                vm_wait0();   // wave0's coh stores complete (at IC) before tag
                __hip_atomic_store(&tag1[w * 32], t, __ATOMIC_RELAXED, __HIP_MEMORY_SCOPE_AGENT);
            }

            // ---------- stage2: owner WG (w==b) reduces + argmax + publishes ----------
            if (w < 64) {
                if (tid < 256) {
                    int v;
                    do {
                        __builtin_amdgcn_s_sleep(1);
                        v = __hip_atomic_load(&tag1[tid * 32], __ATOMIC_RELAXED, __HIP_MEMORY_SCOPE_AGENT);
                    } while (v < t);
                }
                __syncthreads();
                if (tid < 704) {
                    int cc = tid >> 6, i = tid & 63;
                    const float* pb = pbuf + ((long)(w * 11 + cc) << 8);
                    float s = 0.f;
                    #pragma unroll
                    for (int u = 0; u < 4; ++u)
                        s += __hip_atomic_load(&pb[i + (u << 6)], __ATOMIC_RELAXED, __HIP_MEMORY_SCOPE_AGENT);
                    #pragma unroll
                    for (int off = 32; off; off >>= 1) s += __shfl_down(s, off);
                    if (i == 0) slog[cc] = s + p.b2[cc];
                }
                __syncthreads();
                if (tid == 0) {
                    float best = -3.4e38f; int am = 0;
                    #pragma unroll
                    for (int cc = 0; cc < 11; ++cc) {
                        float v = slog[cc];
                        p.out[(long)w * (Tn * 11) + (long)(t - 1) * 11 + cc] = v;
                        if (v > best) { best = v; am = cc; }
                    }
                    __hip_atomic_store(&ptag[w * 32], (t << 4) | am, __ATOMIC_RELAXED, __HIP_MEMORY_SCOPE_AGENT);
                }
            }
        }
        if (t == Tn) break;

        // ---------- gates0 GEMM (K=768) + prevl poll + LSTM0 elementwise ----------
        {
            Seg sg[2];
            sg[0] = { p.mainf + (long)t * 256, (long)Tn * 256, 0, 256, Wcomb, 256, 0, 0 };
            sg[1] = { h0T + prv * 32768, 0, 1, 512, p.Whh0, 512, 0, 1 };
            float ga = mm_run<8>(sg, 2 * w, 512, tid, b, actA, actB, wA, wB, red);
            if (tid < 64) {
                if (t >= 1) {
                    int v;
                    do {
                        __builtin_amdgcn_s_sleep(1);
                        v = __hip_atomic_load(&ptag[tid * 32], __ATOMIC_RELAXED, __HIP_MEMORY_SCOPE_AGENT);
                    } while ((v >> 4) < t);
                    prevlS[tid] = v & 15;
                } else prevlS[tid] = 0;
            }
            __syncthreads();
            if (tid < 512) {
                int rr_ = tid >> 6;
                int jrow = (rr_ >> 1) * 512 + 2 * w + (rr_ & 1);
                int pv = prevlS[b];
                red[rr_][b] = ga + bc0v[jrow] + embg[pv * 2048 + jrow];
            }
            __syncthreads();
            if (tid < 128) {
                int jj = tid >> 6, k = 2 * w + jj;
                float g0 = red[jj][b], g1 = red[2 + jj][b], g2 = red[4 + jj][b], g3 = red[6 + jj][b];
                float ci = c0T[k * 64 + b];
                float cn = sigm(g1) * ci + sigm(g0) * tanhf(g2);
                c0T[k * 64 + b] = cn;                          // CU-private: plain
                coh_store(&h0T[cur * 32768 + k * 64 + b], sigm(g3) * tanhf(cn));
            }
        }
        gsync(done, arr, w, ++gen);

        // ---------- gates1 GEMM (K=1024) + LSTM1 elementwise ----------
        {
            Seg sg[2];
            sg[0] = { h0T + cur * 32768, 0, 1, 512, p.Wih1, 512, 0, 1 };
            sg[1] = { h1T + prv * 32768, 0, 1, 512, p.Whh1, 512, 0, 1 };
            float ga = mm_run<8>(sg, 2 * w, 512, tid, b, actA, actB, wA, wB, red);
            __syncthreads();
            if (tid < 512) {
                int rr_ = tid >> 6;
                int jrow = (rr_ >> 1) * 512 + 2 * w + (rr_ & 1);
                red[rr_][b] = ga + p.bih1[jrow] + p.bhh1[jrow];
            }
            __syncthreads();
            if (tid < 128) {
                int jj = tid >> 6, k = 2 * w + jj;
                float g0 = red[jj][b], g1 = red[2 + jj][b], g2 = red[4 + jj][b], g3 = red[6 + jj][b];
                float ci = c1T[k * 64 + b];
                float cn = sigm(g1) * ci + sigm(g0) * tanhf(g2);
                c1T[k * 64 + b] = cn;
                coh_store(&h1T[cur * 32768 + k * 64 + b], sigm(g3) * tanhf(cn));
            }
        }
        gsync(done, arr, w, ++gen);
    }
}

// ---------------- launch ----------------
extern "C" void kernel_launch(void* const* d_in, const int* in_sizes, int n_in,
                              void* d_out, int out_size, void* d_ws, size_t ws_size,
                              hipStream_t stream) {
    const float* mainf = (const float*)d_in[0];
    const float* phys  = (const float*)d_in[1];
    // d_in[2] = mask (unused)
    const float* Wp   = (const float*)d_in[3];
    const float* bp   = (const float*)d_in[4];
    const float* emb  = (const float*)d_in[5];
    const float* Wih0 = (const float*)d_in[6];
    const float* Whh0 = (const float*)d_in[7];
    const float* bih0 = (const float*)d_in[8];
    const float* bhh0 = (const float*)d_in[9];
    const float* Wih1 = (const float*)d_in[10];
    const float* Whh1 = (const float*)d_in[11];
    const float* bih1 = (const float*)d_in[12];
    const float* bhh1 = (const float*)d_in[13];
    const float* W1   = (const float*)d_in[14];
    const float* b1   = (const float*)d_in[15];
    const float* W2   = (const float*)d_in[16];
    const float* b2   = (const float*)d_in[17];
    float* out = (float*)d_out;
    float* ws  = (float*)d_ws;

    (void)hipMemsetAsync(out + OUT_LOGITS_WORDS, 0, (size_t)OUT_TAIL_WORDS * 4, stream);

    k_wcomb<<<2048, 256, 0, stream>>>(Wih0, Wp, bp, bih0, bhh0, ws);
    k_embg<<<88, 256, 0, stream>>>(emb, Wih0, ws);
    k_zero<<<(ZERO_WORDS + 255) / 256, 256, 0, stream>>>(ws);

    MP p{ mainf, phys, Whh0, Wih1, Whh1, bih1, bhh1, W1, b1, W2, b2, ws, out };
    k_main<<<NWG, NTH, 0, stream>>>(p);
}

// Round 8
// 24778.304 us; speedup vs baseline: 2.7801x; 1.0521x over previous
//
#include <hip/hip_runtime.h>

// ---------------- problem constants ----------------
#define Tn   512
#define NWG  256
#define NTH  1024

// ---------------- ws layout (float words) ----------------
#define OFF_WCOMB 0                      // [2048][256]
#define OFF_BC0   524288                 // [2048]
#define OFF_EMBG  526336                 // [11][2048]
#define OFF_H0T   548864                 // [2][512*64] k-major (zero region start)
#define OFF_H1T   (OFF_H0T + 65536)      // [2][512*64]
#define OFF_C0T   (OFF_H1T + 65536)      // [512*64]
#define OFF_C1T   (OFF_C0T + 32768)
#define OFF_BAR   (OFF_C1T + 32768)      // (unused done flag, kept for layout)
#define OFF_ARR   (OFF_BAR + 32)         // 256 arrival slots * 32
#define OFF_TAG1  (OFF_ARR + 8192)       // 256 head tags * 32
#define OFF_PTAG  (OFF_TAG1 + 8192)      // 64 prev tags * 32
#define ZERO_END  (OFF_PTAG + 2048)
#define ZERO_WORDS (ZERO_END - OFF_H0T)
#define OFF_PBUF  ZERO_END               // [704][256] floats (overwritten each step)
#define WS_WORDS  (OFF_PBUF + 704 * 256)

// out layout: logits [64][512][11] = 360448, zeros 360448, attn 32768
#define OUT_LOGITS_WORDS 360448
#define OUT_TAIL_WORDS   393216

// ---------------- setup kernels ----------------
__global__ void k_wcomb(const float* __restrict__ Wih0, const float* __restrict__ Wp,
                        const float* __restrict__ bp, const float* __restrict__ bih0,
                        const float* __restrict__ bhh0, float* __restrict__ ws) {
    int j = blockIdx.x;            // 0..2047
    int k = threadIdx.x;           // 0..255
    const float* row = Wih0 + (long)j * 1024;
    float acc = 0.f;
    for (int h = 0; h < 512; ++h) acc = fmaf(row[h], Wp[h * 256 + k], acc);
    ws[OFF_WCOMB + j * 256 + k] = acc;
    __shared__ float s[256];
    s[k] = row[k] * bp[k] + row[256 + k] * bp[256 + k];
    __syncthreads();
    for (int st = 128; st > 0; st >>= 1) { if (k < st) s[k] += s[k + st]; __syncthreads(); }
    if (k == 0) ws[OFF_BC0 + j] = bih0[j] + bhh0[j] + s[0];
}

__global__ void k_embg(const float* __restrict__ emb, const float* __restrict__ Wih0,
                       float* __restrict__ ws) {
    int cls = blockIdx.x >> 3;
    int j = ((blockIdx.x & 7) << 8) + threadIdx.x;
    const float* er = emb + cls * 512;
    const float* wr = Wih0 + (long)j * 1024 + 512;
    float acc = 0.f;
    for (int h = 0; h < 512; ++h) acc = fmaf(er[h], wr[h], acc);
    ws[OFF_EMBG + cls * 2048 + j] = acc;
}

// zero state + tags/barrier (MUST run every launch: graph replays reuse ws)
__global__ void k_zero(float* __restrict__ ws) {
    long i = (long)blockIdx.x * blockDim.x + threadIdx.x;
    if (i < ZERO_WORDS) ws[OFF_H0T + i] = 0.f;
}

// ---------------- main persistent kernel ----------------
struct MP {
    const float *mainf, *phys, *Whh0, *Wih1, *Whh1, *bih1, *bhh1, *W1, *b1, *W2, *b2;
    float* ws;
    float* out;
};

struct Seg {
    const float* act;   // base
    long rs;            // row stride (b-major)
    int kmaj;           // 1: act[k*64+b]  0: act[b*rs+k]
    int klen;
    const float* wgt;   // weight base, row-major
    int wld;
    int wcol0;
    int coh;            // 1: stage act via sc0/sc1 bypass loads (cross-XCD data)
};

__device__ __forceinline__ float sigm(float x) { return 1.f / (1.f + expf(-x)); }

// coherent 16B load: bypass L1+L2, read from IC (cross-XCD-safe)
__device__ __forceinline__ void coh_issue16(const float* p, float4& v) {
    asm volatile("global_load_dwordx4 %0, %1, off sc0 sc1" : "=&v"(v) : "v"(p));
}
__device__ __forceinline__ void vm_wait0() {
    asm volatile("s_waitcnt vmcnt(0)" ::: "memory");
}
// coherent 4B store: write-through to IC (no fence needed for visibility)
__device__ __forceinline__ void coh_store(float* p, float v) {
    __hip_atomic_store(p, v, __ATOMIC_RELAXED, __HIP_MEMORY_SCOPE_AGENT);
}

// CHUNK = 128 k-rows per staged tile.
__device__ __forceinline__ void resolve(int ch, int nch0, const Seg* sg, int& s, int& k0, int& kc) {
    if (ch < nch0) { s = 0; k0 = ch << 7; }
    else           { s = 1; k0 = (ch - nch0) << 7; }
    kc = sg[s].klen - k0; if (kc > 128) kc = 128;
}

// acc = sum_k act[b][k] * W[jrow(r)][k];  jrow(r) = (r>>1)*jstride + j0 + (r&1).
// Threads: b = tid&63, rq = tid>>6; r = rq & (NR-1), q = rq / NR (2-way K-split).
// Proven r6 hazard ordering per iteration: issue -> vm_wait -> LDS write ->
// __syncthreads -> compute -> __syncthreads. No asm regs live across barriers.
template <int NR>
__device__ float mm_run(const Seg* sg, int j0, int jstride, int tid, int b,
                        float (*actA)[72], float (*actB)[72],
                        float (*wA)[132], float (*wB)[132], float (*red)[64]) {
    const int rq = tid >> 6;
    const int r = rq & (NR - 1);
    const int q = rq / NR;
    const int nch0 = (sg[0].klen + 127) >> 7;
    const int nch = nch0 + ((sg[1].klen + 127) >> 7);
    const int nq0 = (nch + 1) >> 1;
    float acc = 0.f;
    for (int it = 0; it < nq0; ++it) {
        const int chA = it, chB = nq0 + it;
        const bool hasB = chB < nch;
        int sA, kA, kcA; resolve(chA, nch0, sg, sA, kA, kcA);
        int sB = 0, kB = 0, kcB = 0;
        if (hasB) resolve(chB, nch0, sg, sB, kB, kcB);
        const Seg gA = sg[sA];
        const Seg gB = sg[sB];

        // ---- issue act loads: 2 slots/thread/buffer (keep all in flight) ----
        float4 va0, va1, vb0, vb1;
        bool fA0 = false, fA1 = false, fB0 = false, fB1 = false, coh = false;
        if (gA.kmaj) {
            int kk0 = tid >> 4, b4 = tid & 15;          // slot tid  : kk 0..63
            int kk1 = kk0 + 64;                          // slot +1024: kk 64..127
            fA0 = kk0 < kcA; fA1 = kk1 < kcA;
            if (fA0) { const float* p = gA.act + ((long)(kA + kk0) << 6) + (b4 << 2);
                       if (gA.coh) { coh_issue16(p, va0); coh = true; } else va0 = *(const float4*)p; }
            if (fA1) { const float* p = gA.act + ((long)(kA + kk1) << 6) + (b4 << 2);
                       if (gA.coh) { coh_issue16(p, va1); coh = true; } else va1 = *(const float4*)p; }
        } else {
            int k40 = tid >> 6, bb = tid & 63;          // slot tid  : k4 0..15
            int k41 = k40 + 16;                          // slot +1024: k4 16..31
            fA0 = (k40 << 2) < kcA; fA1 = (k41 << 2) < kcA;
            if (fA0) { const float* p = gA.act + (long)bb * gA.rs + kA + (k40 << 2);
                       if (gA.coh) { coh_issue16(p, va0); coh = true; } else va0 = *(const float4*)p; }
            if (fA1) { const float* p = gA.act + (long)bb * gA.rs + kA + (k41 << 2);
                       if (gA.coh) { coh_issue16(p, va1); coh = true; } else va1 = *(const float4*)p; }
        }
        if (hasB) {
            if (gB.kmaj) {
                int kk0 = tid >> 4, b4 = tid & 15;
                int kk1 = kk0 + 64;
                fB0 = kk0 < kcB; fB1 = kk1 < kcB;
                if (fB0) { const float* p = gB.act + ((long)(kB + kk0) << 6) + (b4 << 2);
                           if (gB.coh) { coh_issue16(p, vb0); coh = true; } else vb0 = *(const float4*)p; }
                if (fB1) { const float* p = gB.act + ((long)(kB + kk1) << 6) + (b4 << 2);
                           if (gB.coh) { coh_issue16(p, vb1); coh = true; } else vb1 = *(const float4*)p; }
            } else {
                int k40 = tid >> 6, bb = tid & 63;
                int k41 = k40 + 16;
                fB0 = (k40 << 2) < kcB; fB1 = (k41 << 2) < kcB;
                if (fB0) { const float* p = gB.act + (long)bb * gB.rs + kB + (k40 << 2);
                           if (gB.coh) { coh_issue16(p, vb0); coh = true; } else vb0 = *(const float4*)p; }
                if (fB1) { const float* p = gB.act + (long)bb * gB.rs + kB + (k41 << 2);
                           if (gB.coh) { coh_issue16(p, vb1); coh = true; } else vb1 = *(const float4*)p; }
            }
        }
        // ---- weights: 1 float/thread (rw = tid>>7 in 0..7, kk = tid&127) ----
        float wva = 0.f, wvb = 0.f;
        const int rw = tid >> 7, kkw = tid & 127;
        const bool wact = rw < NR;
        if (wact) {
            int j = (rw >> 1) * jstride + j0 + (rw & 1);
            if (kkw < kcA) wva = gA.wgt[(long)j * gA.wld + gA.wcol0 + kA + kkw];
            if (hasB && kkw < kcB) wvb = gB.wgt[(long)j * gB.wld + gB.wcol0 + kB + kkw];
        }
        if (coh) vm_wait0();
        // ---- LDS writes ----
        if (gA.kmaj) {
            int kk0 = tid >> 4, b4 = tid & 15;
            if (fA0) *(float4*)&actA[kk0][b4 << 2] = va0;
            if (fA1) *(float4*)&actA[kk0 + 64][b4 << 2] = va1;
        } else {
            int k40 = tid >> 6, bb = tid & 63;
            if (fA0) { actA[(k40 << 2) + 0][bb] = va0.x; actA[(k40 << 2) + 1][bb] = va0.y;
                       actA[(k40 << 2) + 2][bb] = va0.z; actA[(k40 << 2) + 3][bb] = va0.w; }
            if (fA1) { int k41 = k40 + 16;
                       actA[(k41 << 2) + 0][bb] = va1.x; actA[(k41 << 2) + 1][bb] = va1.y;
                       actA[(k41 << 2) + 2][bb] = va1.z; actA[(k41 << 2) + 3][bb] = va1.w; }
        }
        if (hasB) {
            if (gB.kmaj) {
                int kk0 = tid >> 4, b4 = tid & 15;
                if (fB0) *(float4*)&actB[kk0][b4 << 2] = vb0;
                if (fB1) *(float4*)&actB[kk0 + 64][b4 << 2] = vb1;
            } else {
                int k40 = tid >> 6, bb = tid & 63;
                if (fB0) { actB[(k40 << 2) + 0][bb] = vb0.x; actB[(k40 << 2) + 1][bb] = vb0.y;
                           actB[(k40 << 2) + 2][bb] = vb0.z; actB[(k40 << 2) + 3][bb] = vb0.w; }
                if (fB1) { int k41 = k40 + 16;
                           actB[(k41 << 2) + 0][bb] = vb1.x; actB[(k41 << 2) + 1][bb] = vb1.y;
                           actB[(k41 << 2) + 2][bb] = vb1.z; actB[(k41 << 2) + 3][bb] = vb1.w; }
            }
        }
        if (wact) {
            if (kkw < kcA) wA[rw][kkw] = wva;
            if (hasB && kkw < kcB) wB[rw][kkw] = wvb;
        }
        __syncthreads();
        // ---- compute ----
        if (tid < NR * 128) {
            const int myc = q ? chB : chA;
            if (myc < nch) {
                int s_, k0c, kc; resolve(myc, nch0, sg, s_, k0c, kc);
                float (*at)[72] = q ? actB : actA;
                float (*wv)[132] = q ? wB : wA;
                const int n4 = kc >> 2;
                #pragma unroll 8
                for (int k4 = 0; k4 < n4; ++k4) {
                    float a0 = at[(k4 << 2) + 0][b];
                    float a1 = at[(k4 << 2) + 1][b];
                    float a2 = at[(k4 << 2) + 2][b];
                    float a3 = at[(k4 << 2) + 3][b];
                    float4 w4 = *(const float4*)&wv[r][k4 << 2];
                    acc = fmaf(a0, w4.x, acc);
                    acc = fmaf(a1, w4.y, acc);
                    acc = fmaf(a2, w4.z, acc);
                    acc = fmaf(a3, w4.w, acc);
                }
            }
        }
        __syncthreads();
    }
    if (rq >= NR && rq < NR * 2) red[r][b] = acc;   // q==1 partial
    __syncthreads();
    if (rq < NR) acc += red[r][b];                  // q==0 owner
    return acc;
}

// All-poll barrier: each WG posts its own arrival slot; 256 threads of EVERY
// WG poll one slot each (read-only, IC broadcast). No RMW, no aggregator hop.
__device__ __forceinline__ void gsync(int* arr, int w, int gen) {
    vm_wait0();
    __syncthreads();
    const int tid = threadIdx.x;
    if (tid == 0)
        __hip_atomic_store(&arr[w * 32], gen, __ATOMIC_RELAXED, __HIP_MEMORY_SCOPE_AGENT);
    if (tid < NWG) {
        int v;
        do {
            __builtin_amdgcn_s_sleep(1);
            v = __hip_atomic_load(&arr[tid * 32], __ATOMIC_RELAXED, __HIP_MEMORY_SCOPE_AGENT);
        } while (v < gen);
    }
    __syncthreads();
}

__global__ void __launch_bounds__(NTH, 4) k_main(MP p) {
    float* ws = p.ws;
    const float* Wcomb = ws + OFF_WCOMB;
    const float* bc0v  = ws + OFF_BC0;
    const float* embg  = ws + OFF_EMBG;
    float* h0T = ws + OFF_H0T;
    float* h1T = ws + OFF_H1T;
    float* c0T = ws + OFF_C0T;
    float* c1T = ws + OFF_C1T;
    float* pbuf = ws + OFF_PBUF;            // [704][256]
    int* arr  = (int*)(ws + OFF_ARR);
    int* tag1 = (int*)(ws + OFF_TAG1);
    int* ptag = (int*)(ws + OFF_PTAG);

    __shared__ float actA[128][72], actB[128][72];   // 73.7 KB
    __shared__ float wA[8][132], wB[8][132];         //  8.4 KB
    __shared__ float red[8][64];
    __shared__ float rrow[2][64];
    __shared__ float slog[11];
    __shared__ int prevlS[64];

    const int w = blockIdx.x, tid = threadIdx.x, b = tid & 63;
    int gen = 0;

    for (int t = 0; t <= Tn; ++t) {
        const int cur = t & 1, prv = cur ^ 1;

        // ---------- head partials for step t-1 (all 256 WGs, 2 W1-rows each) ----------
        if (t >= 1) {
            Seg sg[2];
            sg[0] = { h1T + prv * 32768, 0, 1, 512, p.W1, 544, 0, 1 };
            sg[1] = { p.phys + (long)(t - 1) * 32, (long)Tn * 32, 0, 32, p.W1, 544, 512, 0 };
            float ha = mm_run<2>(sg, 2 * w, 512, tid, b, actA, actB, wA, wB, red);
            if (tid < 128) {
                float rr = ha + p.b1[2 * w + (tid >> 6)];
                rrow[tid >> 6][b] = rr > 0.f ? rr : 0.f;
            }
            __syncthreads();
            if (tid < 64) {
                float r0 = rrow[0][b], r1 = rrow[1][b];
                #pragma unroll
                for (int cc = 0; cc < 11; ++cc)
                    coh_store(&pbuf[((long)(b * 11 + cc) << 8) + w],
                              fmaf(r0, p.W2[cc * 512 + 2 * w], r1 * p.W2[cc * 512 + 2 * w + 1]));
            }
            if (tid == 0) {
                vm_wait0();   // wave0's coh stores at IC before tag
                __hip_atomic_store(&tag1[w * 32], t, __ATOMIC_RELAXED, __HIP_MEMORY_SCOPE_AGENT);
            }

            // ---------- stage2: owner WG (w==b) reduces + argmax + publishes ----------
            if (w < 64) {
                if (tid < 256) {
                    int v;
                    do {
                        __builtin_amdgcn_s_sleep(1);
                        v = __hip_atomic_load(&tag1[tid * 32], __ATOMIC_RELAXED, __HIP_MEMORY_SCOPE_AGENT);
                    } while (v < t);
                }
                __syncthreads();
                if (tid < 704) {
                    int cc = tid >> 6, i = tid & 63;
                    const float* pb = pbuf + ((long)(w * 11 + cc) << 8);
                    float s = 0.f;
                    #pragma unroll
                    for (int u = 0; u < 4; ++u)
                        s += __hip_atomic_load(&pb[i + (u << 6)], __ATOMIC_RELAXED, __HIP_MEMORY_SCOPE_AGENT);
                    #pragma unroll
                    for (int off = 32; off; off >>= 1) s += __shfl_down(s, off);
                    if (i == 0) slog[cc] = s + p.b2[cc];
                }
                __syncthreads();
                if (tid == 0) {
                    float best = -3.4e38f; int am = 0;
                    #pragma unroll
                    for (int cc = 0; cc < 11; ++cc) {
                        float v = slog[cc];
                        p.out[(long)w * (Tn * 11) + (long)(t - 1) * 11 + cc] = v;
                        if (v > best) { best = v; am = cc; }
                    }
                    __hip_atomic_store(&ptag[w * 32], (t << 4) | am, __ATOMIC_RELAXED, __HIP_MEMORY_SCOPE_AGENT);
                }
            }
        }
        if (t == Tn) break;

        // ---------- gates0 GEMM (K=768) + prevl poll + LSTM0 elementwise ----------
        {
            Seg sg[2];
            sg[0] = { p.mainf + (long)t * 256, (long)Tn * 256, 0, 256, Wcomb, 256, 0, 0 };
            sg[1] = { h0T + prv * 32768, 0, 1, 512, p.Whh0, 512, 0, 1 };
            float ga = mm_run<8>(sg, 2 * w, 512, tid, b, actA, actB, wA, wB, red);
            if (tid < 64) {
                if (t >= 1) {
                    int v;
                    do {
                        __builtin_amdgcn_s_sleep(1);
                        v = __hip_atomic_load(&ptag[tid * 32], __ATOMIC_RELAXED, __HIP_MEMORY_SCOPE_AGENT);
                    } while ((v >> 4) < t);
                    prevlS[tid] = v & 15;
                } else prevlS[tid] = 0;
            }
            __syncthreads();
            if (tid < 512) {
                int rr_ = tid >> 6;
                int jrow = (rr_ >> 1) * 512 + 2 * w + (rr_ & 1);
                int pv = prevlS[b];
                red[rr_][b] = ga + bc0v[jrow] + embg[pv * 2048 + jrow];
            }
            __syncthreads();
            if (tid < 128) {
                int jj = tid >> 6, k = 2 * w + jj;
                float g0 = red[jj][b], g1 = red[2 + jj][b], g2 = red[4 + jj][b], g3 = red[6 + jj][b];
                float ci = c0T[k * 64 + b];
                float cn = sigm(g1) * ci + sigm(g0) * tanhf(g2);
                c0T[k * 64 + b] = cn;                          // CU-private: plain
                coh_store(&h0T[cur * 32768 + k * 64 + b], sigm(g3) * tanhf(cn));
            }
        }
        gsync(arr, w, ++gen);

        // ---------- gates1 GEMM (K=1024) + LSTM1 elementwise ----------
        {
            Seg sg[2];
            sg[0] = { h0T + cur * 32768, 0, 1, 512, p.Wih1, 512, 0, 1 };
            sg[1] = { h1T + prv * 32768, 0, 1, 512, p.Whh1, 512, 0, 1 };
            float ga = mm_run<8>(sg, 2 * w, 512, tid, b, actA, actB, wA, wB, red);
            __syncthreads();
            if (tid < 512) {
                int rr_ = tid >> 6;
                int jrow = (rr_ >> 1) * 512 + 2 * w + (rr_ & 1);
                red[rr_][b] = ga + p.bih1[jrow] + p.bhh1[jrow];
            }
            __syncthreads();
            if (tid < 128) {
                int jj = tid >> 6, k = 2 * w + jj;
                float g0 = red[jj][b], g1 = red[2 + jj][b], g2 = red[4 + jj][b], g3 = red[6 + jj][b];
                float ci = c1T[k * 64 + b];
                float cn = sigm(g1) * ci + sigm(g0) * tanhf(g2);
                c1T[k * 64 + b] = cn;
                coh_store(&h1T[cur * 32768 + k * 64 + b], sigm(g3) * tanhf(cn));
            }
        }
        gsync(arr, w, ++gen);
    }
}

// ---------------- launch ----------------
extern "C" void kernel_launch(void* const* d_in, const int* in_sizes, int n_in,
                              void* d_out, int out_size, void* d_ws, size_t ws_size,
                              hipStream_t stream) {
    const float* mainf = (const float*)d_in[0];
    const float* phys  = (const float*)d_in[1];
    // d_in[2] = mask (unused)
    const float* Wp   = (const float*)d_in[3];
    const float* bp   = (const float*)d_in[4];
    const float* emb  = (const float*)d_in[5];
    const float* Wih0 = (const float*)d_in[6];
    const float* Whh0 = (const float*)d_in[7];
    const float* bih0 = (const float*)d_in[8];
    const float* bhh0 = (const float*)d_in[9];
    const float* Wih1 = (const float*)d_in[10];
    const float* Whh1 = (const float*)d_in[11];
    const float* bih1 = (const float*)d_in[12];
    const float* bhh1 = (const float*)d_in[13];
    const float* W1   = (const float*)d_in[14];
    const float* b1   = (const float*)d_in[15];
    const float* W2   = (const float*)d_in[16];
    const float* b2   = (const float*)d_in[17];
    float* out = (float*)d_out;
    float* ws  = (float*)d_ws;

    (void)hipMemsetAsync(out + OUT_LOGITS_WORDS, 0, (size_t)OUT_TAIL_WORDS * 4, stream);

    k_wcomb<<<2048, 256, 0, stream>>>(Wih0, Wp, bp, bih0, bhh0, ws);
    k_embg<<<88, 256, 0, stream>>>(emb, Wih0, ws);
    k_zero<<<(ZERO_WORDS + 255) / 256, 256, 0, stream>>>(ws);

    MP p{ mainf, phys, Whh0, Wih1, Whh1, bih1, bhh1, W1, b1, W2, b2, ws, out };
    k_main<<<NWG, NTH, 0, stream>>>(p);
}

// Round 9
// 19513.577 us; speedup vs baseline: 3.5302x; 1.2698x over previous
//
#include <hip/hip_runtime.h>

// ---------------- problem constants ----------------
#define Tn   512
#define NWG  256
#define NTH  1024

// ---------------- ws layout (float words) ----------------
#define OFF_WCOMB 0                      // [2048][256]
#define OFF_BC0   524288                 // [2048]
#define OFF_EMBG  526336                 // [11][2048]
#define OFF_H0T   548864                 // [2][512*64] k-major (zero region start)
#define OFF_H1T   (OFF_H0T + 65536)      // [2][512*64]
#define OFF_C0T   (OFF_H1T + 65536)      // [512*64]
#define OFF_C1T   (OFF_C0T + 32768)
#define OFF_BAR   (OFF_C1T + 32768)      // done flag (32 words)
#define OFF_ARR   (OFF_BAR + 32)         // 256 arrival slots * 32
#define OFF_TAG1  (OFF_ARR + 8192)       // 256 head tags * 32
#define OFF_PTAG  (OFF_TAG1 + 8192)      // 64 prev tags * 32
#define ZERO_END  (OFF_PTAG + 2048)
#define ZERO_WORDS (ZERO_END - OFF_H0T)
#define OFF_PBUF  ZERO_END               // [704][256] floats (overwritten each step)
#define WS_WORDS  (OFF_PBUF + 704 * 256)

// out layout: logits [64][512][11] = 360448, zeros 360448, attn 32768
#define OUT_LOGITS_WORDS 360448
#define OUT_TAIL_WORDS   393216

// ---------------- setup kernels ----------------
__global__ void k_wcomb(const float* __restrict__ Wih0, const float* __restrict__ Wp,
                        const float* __restrict__ bp, const float* __restrict__ bih0,
                        const float* __restrict__ bhh0, float* __restrict__ ws) {
    int j = blockIdx.x;            // 0..2047
    int k = threadIdx.x;           // 0..255
    const float* row = Wih0 + (long)j * 1024;
    float acc = 0.f;
    for (int h = 0; h < 512; ++h) acc = fmaf(row[h], Wp[h * 256 + k], acc);
    ws[OFF_WCOMB + j * 256 + k] = acc;
    __shared__ float s[256];
    s[k] = row[k] * bp[k] + row[256 + k] * bp[256 + k];
    __syncthreads();
    for (int st = 128; st > 0; st >>= 1) { if (k < st) s[k] += s[k + st]; __syncthreads(); }
    if (k == 0) ws[OFF_BC0 + j] = bih0[j] + bhh0[j] + s[0];
}

__global__ void k_embg(const float* __restrict__ emb, const float* __restrict__ Wih0,
                       float* __restrict__ ws) {
    int cls = blockIdx.x >> 3;
    int j = ((blockIdx.x & 7) << 8) + threadIdx.x;
    const float* er = emb + cls * 512;
    const float* wr = Wih0 + (long)j * 1024 + 512;
    float acc = 0.f;
    for (int h = 0; h < 512; ++h) acc = fmaf(er[h], wr[h], acc);
    ws[OFF_EMBG + cls * 2048 + j] = acc;
}

// zero state + tags/barrier (MUST run every launch: graph replays reuse ws)
__global__ void k_zero(float* __restrict__ ws) {
    long i = (long)blockIdx.x * blockDim.x + threadIdx.x;
    if (i < ZERO_WORDS) ws[OFF_H0T + i] = 0.f;
}

// ---------------- main persistent kernel ----------------
struct MP {
    const float *mainf, *phys, *Whh0, *Wih1, *Whh1, *bih1, *bhh1, *W1, *b1, *W2, *b2;
    float* ws;
    float* out;
};

struct Seg {
    const float* act;   // base
    long rs;            // row stride (b-major)
    int kmaj;           // 1: act[k*64+b]  0: act[b*rs+k]
    int klen;
    const float* wgt;   // weight base, row-major
    int wld;
    int wcol0;
    int coh;            // 1: stage act via sc0/sc1 bypass loads (cross-XCD data)
};

__device__ __forceinline__ float sigm(float x) { return 1.f / (1.f + expf(-x)); }

// coherent 16B load: bypass L1+L2, read from IC (cross-XCD-safe)
__device__ __forceinline__ void coh_issue16(const float* p, float4& v) {
    asm volatile("global_load_dwordx4 %0, %1, off sc0 sc1" : "=&v"(v) : "v"(p));
}
__device__ __forceinline__ void vm_wait0() {
    asm volatile("s_waitcnt vmcnt(0)" ::: "memory");
}
// coherent 4B store: write-through to IC (no fence needed for visibility)
__device__ __forceinline__ void coh_store(float* p, float v) {
    __hip_atomic_store(p, v, __ATOMIC_RELAXED, __HIP_MEMORY_SCOPE_AGENT);
}

// CHUNK = 128 k-rows per staged tile.
__device__ __forceinline__ void resolve(int ch, int nch0, const Seg* sg, int& s, int& k0, int& kc) {
    if (ch < nch0) { s = 0; k0 = ch << 7; }
    else           { s = 1; k0 = (ch - nch0) << 7; }
    kc = sg[s].klen - k0; if (kc > 128) kc = 128;
}

// 4x4 (or 2x4) register tile: rows rg*NRH+jr, batches 4*b4+jb, k-slice q.
// Per chunk: 4 act ds_read_b128 + NRH w ds_read_b128 feed NRH*16 FMA.
template <int NRH>
__device__ __forceinline__ void comp_tile(const float (*at)[72], const float (*wv)[132],
                                          int rg, int q, int b4, float* acc) {
    float4 a0 = *(const float4*)&at[4 * q + 0][b4 << 2];
    float4 a1 = *(const float4*)&at[4 * q + 1][b4 << 2];
    float4 a2 = *(const float4*)&at[4 * q + 2][b4 << 2];
    float4 a3 = *(const float4*)&at[4 * q + 3][b4 << 2];
    #pragma unroll
    for (int jr = 0; jr < NRH; ++jr) {
        float4 w4 = *(const float4*)&wv[rg * NRH + jr][q << 2];
        acc[jr * 4 + 0] = fmaf(w4.x, a0.x, acc[jr * 4 + 0]);
        acc[jr * 4 + 0] = fmaf(w4.y, a1.x, acc[jr * 4 + 0]);
        acc[jr * 4 + 0] = fmaf(w4.z, a2.x, acc[jr * 4 + 0]);
        acc[jr * 4 + 0] = fmaf(w4.w, a3.x, acc[jr * 4 + 0]);
        acc[jr * 4 + 1] = fmaf(w4.x, a0.y, acc[jr * 4 + 1]);
        acc[jr * 4 + 1] = fmaf(w4.y, a1.y, acc[jr * 4 + 1]);
        acc[jr * 4 + 1] = fmaf(w4.z, a2.y, acc[jr * 4 + 1]);
        acc[jr * 4 + 1] = fmaf(w4.w, a3.y, acc[jr * 4 + 1]);
        acc[jr * 4 + 2] = fmaf(w4.x, a0.z, acc[jr * 4 + 2]);
        acc[jr * 4 + 2] = fmaf(w4.y, a1.z, acc[jr * 4 + 2]);
        acc[jr * 4 + 2] = fmaf(w4.z, a2.z, acc[jr * 4 + 2]);
        acc[jr * 4 + 2] = fmaf(w4.w, a3.z, acc[jr * 4 + 2]);
        acc[jr * 4 + 3] = fmaf(w4.x, a0.w, acc[jr * 4 + 3]);
        acc[jr * 4 + 3] = fmaf(w4.y, a1.w, acc[jr * 4 + 3]);
        acc[jr * 4 + 3] = fmaf(w4.z, a2.w, acc[jr * 4 + 3]);
        acc[jr * 4 + 3] = fmaf(w4.w, a3.w, acc[jr * 4 + 3]);
    }
}

// Returns the full dot for row jrow(tid>>6), batch tid&63 on threads tid < NR*64
// (same contract as previous mm_run). Staging identical to round 8 (proven).
template <int NR>
__device__ float mm_run(const Seg* sg, int j0, int jstride, int tid, int b,
                        float (*actA)[72], float (*actB)[72],
                        float (*wA)[132], float (*wB)[132], float* redw) {
    constexpr int NRH = NR / 2;      // rows per thread
    constexpr int NA = NRH * 4;      // accumulators per thread
    const int b4 = tid & 15;
    const int q  = (tid >> 4) & 31;
    const int rg = tid >> 9;
    const int nch0 = (sg[0].klen + 127) >> 7;
    const int nch = nch0 + ((sg[1].klen + 127) >> 7);
    const int nq0 = (nch + 1) >> 1;
    float acc[NA];
    #pragma unroll
    for (int i = 0; i < NA; ++i) acc[i] = 0.f;

    for (int it = 0; it < nq0; ++it) {
        const int chA = it, chB = nq0 + it;
        const bool hasB = chB < nch;
        int sA, kA, kcA; resolve(chA, nch0, sg, sA, kA, kcA);
        int sB = 0, kB = 0, kcB = 0;
        if (hasB) resolve(chB, nch0, sg, sB, kB, kcB);
        const Seg gA = sg[sA];
        const Seg gB = sg[sB];

        // ---- issue act loads: 2 slots/thread/buffer (r8-proven) ----
        float4 va0, va1, vb0, vb1;
        bool fA0 = false, fA1 = false, fB0 = false, fB1 = false, coh = false;
        if (gA.kmaj) {
            int kk0 = tid >> 4, b4s = tid & 15;
            int kk1 = kk0 + 64;
            fA0 = kk0 < kcA; fA1 = kk1 < kcA;
            if (fA0) { const float* p = gA.act + ((long)(kA + kk0) << 6) + (b4s << 2);
                       if (gA.coh) { coh_issue16(p, va0); coh = true; } else va0 = *(const float4*)p; }
            if (fA1) { const float* p = gA.act + ((long)(kA + kk1) << 6) + (b4s << 2);
                       if (gA.coh) { coh_issue16(p, va1); coh = true; } else va1 = *(const float4*)p; }
        } else {
            int k40 = tid >> 6, bb = tid & 63;
            int k41 = k40 + 16;
            fA0 = (k40 << 2) < kcA; fA1 = (k41 << 2) < kcA;
            if (fA0) { const float* p = gA.act + (long)bb * gA.rs + kA + (k40 << 2);
                       if (gA.coh) { coh_issue16(p, va0); coh = true; } else va0 = *(const float4*)p; }
            if (fA1) { const float* p = gA.act + (long)bb * gA.rs + kA + (k41 << 2);
                       if (gA.coh) { coh_issue16(p, va1); coh = true; } else va1 = *(const float4*)p; }
        }
        if (hasB) {
            if (gB.kmaj) {
                int kk0 = tid >> 4, b4s = tid & 15;
                int kk1 = kk0 + 64;
                fB0 = kk0 < kcB; fB1 = kk1 < kcB;
                if (fB0) { const float* p = gB.act + ((long)(kB + kk0) << 6) + (b4s << 2);
                           if (gB.coh) { coh_issue16(p, vb0); coh = true; } else vb0 = *(const float4*)p; }
                if (fB1) { const float* p = gB.act + ((long)(kB + kk1) << 6) + (b4s << 2);
                           if (gB.coh) { coh_issue16(p, vb1); coh = true; } else vb1 = *(const float4*)p; }
            } else {
                int k40 = tid >> 6, bb = tid & 63;
                int k41 = k40 + 16;
                fB0 = (k40 << 2) < kcB; fB1 = (k41 << 2) < kcB;
                if (fB0) { const float* p = gB.act + (long)bb * gB.rs + kB + (k40 << 2);
                           if (gB.coh) { coh_issue16(p, vb0); coh = true; } else vb0 = *(const float4*)p; }
                if (fB1) { const float* p = gB.act + (long)bb * gB.rs + kB + (k41 << 2);
                           if (gB.coh) { coh_issue16(p, vb1); coh = true; } else vb1 = *(const float4*)p; }
            }
        }
        // ---- weights: 1 float/thread ----
        float wva = 0.f, wvb = 0.f;
        const int rw = tid >> 7, kkw = tid & 127;
        const bool wact = rw < NR;
        if (wact) {
            int j = (rw >> 1) * jstride + j0 + (rw & 1);
            if (kkw < kcA) wva = gA.wgt[(long)j * gA.wld + gA.wcol0 + kA + kkw];
            if (hasB && kkw < kcB) wvb = gB.wgt[(long)j * gB.wld + gB.wcol0 + kB + kkw];
        }
        if (coh) vm_wait0();
        // ---- LDS writes ----
        if (gA.kmaj) {
            int kk0 = tid >> 4, b4s = tid & 15;
            if (fA0) *(float4*)&actA[kk0][b4s << 2] = va0;
            if (fA1) *(float4*)&actA[kk0 + 64][b4s << 2] = va1;
        } else {
            int k40 = tid >> 6, bb = tid & 63;
            if (fA0) { actA[(k40 << 2) + 0][bb] = va0.x; actA[(k40 << 2) + 1][bb] = va0.y;
                       actA[(k40 << 2) + 2][bb] = va0.z; actA[(k40 << 2) + 3][bb] = va0.w; }
            if (fA1) { int k41 = k40 + 16;
                       actA[(k41 << 2) + 0][bb] = va1.x; actA[(k41 << 2) + 1][bb] = va1.y;
                       actA[(k41 << 2) + 2][bb] = va1.z; actA[(k41 << 2) + 3][bb] = va1.w; }
        }
        if (hasB) {
            if (gB.kmaj) {
                int kk0 = tid >> 4, b4s = tid & 15;
                if (fB0) *(float4*)&actB[kk0][b4s << 2] = vb0;
                if (fB1) *(float4*)&actB[kk0 + 64][b4s << 2] = vb1;
            } else {
                int k40 = tid >> 6, bb = tid & 63;
                if (fB0) { actB[(k40 << 2) + 0][bb] = vb0.x; actB[(k40 << 2) + 1][bb] = vb0.y;
                           actB[(k40 << 2) + 2][bb] = vb0.z; actB[(k40 << 2) + 3][bb] = vb0.w; }
                if (fB1) { int k41 = k40 + 16;
                           actB[(k41 << 2) + 0][bb] = vb1.x; actB[(k41 << 2) + 1][bb] = vb1.y;
                           actB[(k41 << 2) + 2][bb] = vb1.z; actB[(k41 << 2) + 3][bb] = vb1.w; }
            }
        }
        if (wact) {
            if (kkw < kcA) wA[rw][kkw] = wva;
            if (hasB && kkw < kcB) wB[rw][kkw] = wvb;
        }
        __syncthreads();
        // ---- compute: register-tiled, q = k4 slice within chunk ----
        {
            int s_, k0c, kc; resolve(chA, nch0, sg, s_, k0c, kc);
            if (4 * q < kc) comp_tile<NRH>(actA, wA, rg, q, b4, acc);
        }
        if (hasB) {
            int s_, k0c, kc; resolve(chB, nch0, sg, s_, k0c, kc);
            if (4 * q < kc) comp_tile<NRH>(actB, wB, rg, q, b4, acc);
        }
        __syncthreads();
    }
    // ---- reduce 32 q-partials: in-wave over 4 q's, then 8-way via LDS ----
    #pragma unroll
    for (int i = 0; i < NA; ++i) {
        acc[i] += __shfl_xor(acc[i], 16);
        acc[i] += __shfl_xor(acc[i], 32);
    }
    const int wv_ = tid >> 6, lane = tid & 63;
    if (lane < 16) {
        float* dst = redw + (((rg * 8 + (wv_ & 7)) * 16) + b4) * NA;
        #pragma unroll
        for (int i = 0; i < NA; ++i) dst[i] = acc[i];
    }
    __syncthreads();
    float out = 0.f;
    if (tid < NR * 64) {
        const int rr = tid >> 6, bb = tid & 63;
        const int rg2 = rr / NRH, jr2 = rr % NRH;
        #pragma unroll
        for (int p_ = 0; p_ < 8; ++p_)
            out += redw[(((rg2 * 8 + p_) * 16) + (bb >> 2)) * NA + jr2 * 4 + (bb & 3)];
    }
    __syncthreads();
    return out;
}

// Hierarchical barrier (r6-proven, stable): per-WG arrival slot, WG0's 256
// threads poll 1 slot each, publish done; others poll the single done flag.
__device__ __forceinline__ void gsync(int* done, int* arr, int w, int gen) {
    vm_wait0();
    __syncthreads();
    const int tid = threadIdx.x;
    if (tid == 0)
        __hip_atomic_store(&arr[w * 32], gen, __ATOMIC_RELAXED, __HIP_MEMORY_SCOPE_AGENT);
    if (w == 0) {
        if (tid < NWG) {
            int v;
            do {
                __builtin_amdgcn_s_sleep(1);
                v = __hip_atomic_load(&arr[tid * 32], __ATOMIC_RELAXED, __HIP_MEMORY_SCOPE_AGENT);
            } while (v < gen);
        }
        __syncthreads();
        if (tid == 0)
            __hip_atomic_store(done, gen, __ATOMIC_RELAXED, __HIP_MEMORY_SCOPE_AGENT);
    } else {
        if (tid == 0) {
            int v;
            do {
                __builtin_amdgcn_s_sleep(2);
                v = __hip_atomic_load(done, __ATOMIC_RELAXED, __HIP_MEMORY_SCOPE_AGENT);
            } while (v < gen);
        }
    }
    __syncthreads();
}

__global__ void __launch_bounds__(NTH, 4) k_main(MP p) {
    float* ws = p.ws;
    const float* Wcomb = ws + OFF_WCOMB;
    const float* bc0v  = ws + OFF_BC0;
    const float* embg  = ws + OFF_EMBG;
    float* h0T = ws + OFF_H0T;
    float* h1T = ws + OFF_H1T;
    float* c0T = ws + OFF_C0T;
    float* c1T = ws + OFF_C1T;
    float* pbuf = ws + OFF_PBUF;            // [704][256]
    int* done = (int*)(ws + OFF_BAR);
    int* arr  = (int*)(ws + OFF_ARR);
    int* tag1 = (int*)(ws + OFF_TAG1);
    int* ptag = (int*)(ws + OFF_PTAG);

    __shared__ float actA[128][72], actB[128][72];   // 73.7 KB
    __shared__ float wA[8][132], wB[8][132];         //  8.4 KB
    __shared__ float redw[2 * 8 * 16 * 16];          // 16 KB (K-split partials)
    __shared__ float red[8][64];                     // gate staging (epilogue)
    __shared__ float rrow[2][64];
    __shared__ float slog[11];
    __shared__ int prevlS[64];

    const int w = blockIdx.x, tid = threadIdx.x, b = tid & 63;
    int gen = 0;

    for (int t = 0; t <= Tn; ++t) {
        const int cur = t & 1, prv = cur ^ 1;

        // ---------- head partials for step t-1 (all 256 WGs, 2 W1-rows each) ----------
        if (t >= 1) {
            Seg sg[2];
            sg[0] = { h1T + prv * 32768, 0, 1, 512, p.W1, 544, 0, 1 };
            sg[1] = { p.phys + (long)(t - 1) * 32, (long)Tn * 32, 0, 32, p.W1, 544, 512, 0 };
            float ha = mm_run<2>(sg, 2 * w, 512, tid, b, actA, actB, wA, wB, redw);
            if (tid < 128) {
                float rr = ha + p.b1[2 * w + (tid >> 6)];
                rrow[tid >> 6][b] = rr > 0.f ? rr : 0.f;
            }
            __syncthreads();
            if (tid < 64) {
                float r0 = rrow[0][b], r1 = rrow[1][b];
                #pragma unroll
                for (int cc = 0; cc < 11; ++cc)
                    coh_store(&pbuf[((long)(b * 11 + cc) << 8) + w],
                              fmaf(r0, p.W2[cc * 512 + 2 * w], r1 * p.W2[cc * 512 + 2 * w + 1]));
            }
            if (tid == 0) {
                vm_wait0();   // wave0's coh stores at IC before tag
                __hip_atomic_store(&tag1[w * 32], t, __ATOMIC_RELAXED, __HIP_MEMORY_SCOPE_AGENT);
            }

            // ---------- stage2: owner WG (w==b) reduces + argmax + publishes ----------
            if (w < 64) {
                if (tid < 256) {
                    int v;
                    do {
                        __builtin_amdgcn_s_sleep(1);
                        v = __hip_atomic_load(&tag1[tid * 32], __ATOMIC_RELAXED, __HIP_MEMORY_SCOPE_AGENT);
                    } while (v < t);
                }
                __syncthreads();
                if (tid < 704) {
                    int cc = tid >> 6, i = tid & 63;
                    const float* pb = pbuf + ((long)(w * 11 + cc) << 8);
                    float s = 0.f;
                    #pragma unroll
                    for (int u = 0; u < 4; ++u)
                        s += __hip_atomic_load(&pb[i + (u << 6)], __ATOMIC_RELAXED, __HIP_MEMORY_SCOPE_AGENT);
                    #pragma unroll
                    for (int off = 32; off; off >>= 1) s += __shfl_down(s, off);
                    if (i == 0) slog[cc] = s + p.b2[cc];
                }
                __syncthreads();
                if (tid == 0) {
                    float best = -3.4e38f; int am = 0;
                    #pragma unroll
                    for (int cc = 0; cc < 11; ++cc) {
                        float v = slog[cc];
                        p.out[(long)w * (Tn * 11) + (long)(t - 1) * 11 + cc] = v;
                        if (v > best) { best = v; am = cc; }
                    }
                    __hip_atomic_store(&ptag[w * 32], (t << 4) | am, __ATOMIC_RELAXED, __HIP_MEMORY_SCOPE_AGENT);
                }
            }
        }
        if (t == Tn) break;

        // ---------- gates0 GEMM (K=768) + prevl poll + LSTM0 elementwise ----------
        {
            Seg sg[2];
            sg[0] = { p.mainf + (long)t * 256, (long)Tn * 256, 0, 256, Wcomb, 256, 0, 0 };
            sg[1] = { h0T + prv * 32768, 0, 1, 512, p.Whh0, 512, 0, 1 };
            float ga = mm_run<8>(sg, 2 * w, 512, tid, b, actA, actB, wA, wB, redw);
            if (tid < 64) {
                if (t >= 1) {
                    int v;
                    do {
                        __builtin_amdgcn_s_sleep(1);
                        v = __hip_atomic_load(&ptag[tid * 32], __ATOMIC_RELAXED, __HIP_MEMORY_SCOPE_AGENT);
                    } while ((v >> 4) < t);
                    prevlS[tid] = v & 15;
                } else prevlS[tid] = 0;
            }
            __syncthreads();
            if (tid < 512) {
                int rr_ = tid >> 6;
                int jrow = (rr_ >> 1) * 512 + 2 * w + (rr_ & 1);
                int pv = prevlS[b];
                red[rr_][b] = ga + bc0v[jrow] + embg[pv * 2048 + jrow];
            }
            __syncthreads();
            if (tid < 128) {
                int jj = tid >> 6, k = 2 * w + jj;
                float g0 = red[jj][b], g1 = red[2 + jj][b], g2 = red[4 + jj][b], g3 = red[6 + jj][b];
                float ci = c0T[k * 64 + b];
                float cn = sigm(g1) * ci + sigm(g0) * tanhf(g2);
                c0T[k * 64 + b] = cn;                          // CU-private: plain
                coh_store(&h0T[cur * 32768 + k * 64 + b], sigm(g3) * tanhf(cn));
            }
        }
        gsync(done, arr, w, ++gen);

        // ---------- gates1 GEMM (K=1024) + LSTM1 elementwise ----------
        {
            Seg sg[2];
            sg[0] = { h0T + cur * 32768, 0, 1, 512, p.Wih1, 512, 0, 1 };
            sg[1] = { h1T + prv * 32768, 0, 1, 512, p.Whh1, 512, 0, 1 };
            float ga = mm_run<8>(sg, 2 * w, 512, tid, b, actA, actB, wA, wB, redw);
            __syncthreads();
            if (tid < 512) {
                int rr_ = tid >> 6;
                int jrow = (rr_ >> 1) * 512 + 2 * w + (rr_ & 1);
                red[rr_][b] = ga + p.bih1[jrow] + p.bhh1[jrow];
            }
            __syncthreads();
            if (tid < 128) {
                int jj = tid >> 6, k = 2 * w + jj;
                float g0 = red[jj][b], g1 = red[2 + jj][b], g2 = red[4 + jj][b], g3 = red[6 + jj][b];
                float ci = c1T[k * 64 + b];
                float cn = sigm(g1) * ci + sigm(g0) * tanhf(g2);
                c1T[k * 64 + b] = cn;
                coh_store(&h1T[cur * 32768 + k * 64 + b], sigm(g3) * tanhf(cn));
            }
        }
        gsync(done, arr, w, ++gen);
    }
}

// ---------------- launch ----------------
extern "C" void kernel_launch(void* const* d_in, const int* in_sizes, int n_in,
                              void* d_out, int out_size, void* d_ws, size_t ws_size,
                              hipStream_t stream) {
    const float* mainf = (const float*)d_in[0];
    const float* phys  = (const float*)d_in[1];
    // d_in[2] = mask (unused)
    const float* Wp   = (const float*)d_in[3];
    const float* bp   = (const float*)d_in[4];
    const float* emb  = (const float*)d_in[5];
    const float* Wih0 = (const float*)d_in[6];
    const float* Whh0 = (const float*)d_in[7];
    const float* bih0 = (const float*)d_in[8];
    const float* bhh0 = (const float*)d_in[9];
    const float* Wih1 = (const float*)d_in[10];
    const float* Whh1 = (const float*)d_in[11];
    const float* bih1 = (const float*)d_in[12];
    const float* bhh1 = (const float*)d_in[13];
    const float* W1   = (const float*)d_in[14];
    const float* b1   = (const float*)d_in[15];
    const float* W2   = (const float*)d_in[16];
    const float* b2   = (const float*)d_in[17];
    float* out = (float*)d_out;
    float* ws  = (float*)d_ws;

    (void)hipMemsetAsync(out + OUT_LOGITS_WORDS, 0, (size_t)OUT_TAIL_WORDS * 4, stream);

    k_wcomb<<<2048, 256, 0, stream>>>(Wih0, Wp, bp, bih0, bhh0, ws);
    k_embg<<<88, 256, 0, stream>>>(emb, Wih0, ws);
    k_zero<<<(ZERO_WORDS + 255) / 256, 256, 0, stream>>>(ws);

    MP p{ mainf, phys, Whh0, Wih1, Whh1, bih1, bhh1, W1, b1, W2, b2, ws, out };
    k_main<<<NWG, NTH, 0, stream>>>(p);
}